// Round 1
// baseline (1409.074 us; speedup 1.0000x reference)
//
#include <hip/hip_runtime.h>

#define NB 2
#define L_SEQ 2048
#define NH 16
#define DKH 64
#define DMODEL 1024

// ---------------------------------------------------------------------------
// Tiled fp32 GEMM: C = A[4096,1024] @ W[1024,1024]
// BM=BN=128, BK=8, 256 threads, 8x8 micro-tile per thread.
// out_mode 0: scatter C[row=(b,l)][col=(h,dk)] into [b][h][l][dk] layout
// out_mode 1: plain row-major [row][col]
// ---------------------------------------------------------------------------
__global__ __launch_bounds__(256)
void gemm128(const float* __restrict__ A, const float* __restrict__ W,
             float* __restrict__ out, const int out_mode)
{
    __shared__ float As[8][128];   // [k][m]
    __shared__ float Bs[8][128];   // [k][n]

    const int t  = threadIdx.x;
    const int tx = t & 15;         // col group
    const int ty = t >> 4;         // row group
    const int m0 = blockIdx.y * 128;
    const int n0 = blockIdx.x * 128;

    const int lm = t >> 1;         // 0..127 (A tile row)
    const int lk = (t & 1) * 4;    // 0 or 4 (A tile col)
    const int bk = t >> 5;         // 0..7   (W tile row)
    const int bn = (t & 31) * 4;   // 0..124 (W tile col)

    float acc[8][8];
#pragma unroll
    for (int i = 0; i < 8; ++i)
#pragma unroll
        for (int j = 0; j < 8; ++j) acc[i][j] = 0.f;

    for (int kt = 0; kt < DMODEL; kt += 8) {
        float4 xa = *(const float4*)&A[(size_t)(m0 + lm) * DMODEL + kt + lk];
        float4 wb = *(const float4*)&W[(size_t)(kt + bk) * DMODEL + n0 + bn];
        __syncthreads();           // previous compute done reading LDS
        As[lk + 0][lm] = xa.x;
        As[lk + 1][lm] = xa.y;
        As[lk + 2][lm] = xa.z;
        As[lk + 3][lm] = xa.w;
        *(float4*)&Bs[bk][bn] = wb;
        __syncthreads();

#pragma unroll
        for (int k = 0; k < 8; ++k) {
            float av[8], bv[8];
            float4 a0 = *(const float4*)&As[k][ty * 8];
            float4 a1 = *(const float4*)&As[k][ty * 8 + 4];
            float4 b0 = *(const float4*)&Bs[k][tx * 8];
            float4 b1 = *(const float4*)&Bs[k][tx * 8 + 4];
            av[0]=a0.x; av[1]=a0.y; av[2]=a0.z; av[3]=a0.w;
            av[4]=a1.x; av[5]=a1.y; av[6]=a1.z; av[7]=a1.w;
            bv[0]=b0.x; bv[1]=b0.y; bv[2]=b0.z; bv[3]=b0.w;
            bv[4]=b1.x; bv[5]=b1.y; bv[6]=b1.z; bv[7]=b1.w;
#pragma unroll
            for (int i = 0; i < 8; ++i)
#pragma unroll
                for (int j = 0; j < 8; ++j)
                    acc[i][j] = fmaf(av[i], bv[j], acc[i][j]);
        }
    }

    if (out_mode == 0) {
#pragma unroll
        for (int i = 0; i < 8; ++i) {
            const int row = m0 + ty * 8 + i;       // = b*L + l
            const int bb  = row >> 11;
            const int l   = row & (L_SEQ - 1);
#pragma unroll
            for (int jg = 0; jg < 2; ++jg) {
                const int col = n0 + tx * 8 + jg * 4;
                const int hh  = col >> 6;
                const int dk  = col & (DKH - 1);
                float4 v = make_float4(acc[i][jg*4+0], acc[i][jg*4+1],
                                       acc[i][jg*4+2], acc[i][jg*4+3]);
                *(float4*)&out[(((size_t)(bb * NH + hh) * L_SEQ + l) << 6) + dk] = v;
            }
        }
    } else {
#pragma unroll
        for (int i = 0; i < 8; ++i) {
            const int row = m0 + ty * 8 + i;
            float4 v0 = make_float4(acc[i][0], acc[i][1], acc[i][2], acc[i][3]);
            float4 v1 = make_float4(acc[i][4], acc[i][5], acc[i][6], acc[i][7]);
            *(float4*)&out[(size_t)row * DMODEL + n0 + tx * 8]     = v0;
            *(float4*)&out[(size_t)row * DMODEL + n0 + tx * 8 + 4] = v1;
        }
    }
}

// ---------------------------------------------------------------------------
// Flash attention (fp32), zero-fill mask BEFORE softmax (masked scores = 0,
// still participate in softmax and PV). One block = (b, h, 64-query tile).
// 256 threads, 4x4 micro-tiles. Q/K staged transposed [d][q] so the S and PV
// inner loops are contiguous ds_read_b128. K and V share one LDS buffer.
// ---------------------------------------------------------------------------
__global__ __launch_bounds__(256)
void attn64(const float* __restrict__ Q, const float* __restrict__ K,
            const float* __restrict__ V, const int* __restrict__ mask,
            float* __restrict__ O)
{
    __shared__ float Qs [64][68];   // [d][q]
    __shared__ float KVs[64][68];   // K phase: [d][k];  V phase: [k][d]
    __shared__ float Ps [64][68];   // [k][q]
    __shared__ unsigned char Msk[64][64];

    const int t  = threadIdx.x;
    const int tx = t & 15;
    const int ty = t >> 4;
    const int b  = blockIdx.z;
    const int h  = blockIdx.y;
    const int q0 = blockIdx.x * 64;

    const size_t headoff = ((size_t)(b * NH + h)) * L_SEQ * DKH;
    const float* Qh = Q + headoff;
    const float* Kh = K + headoff;
    const float* Vh = V + headoff;

    // stage Q tile transposed
#pragma unroll
    for (int c = 0; c < 4; ++c) {
        const int g  = t + 256 * c;
        const int q  = g >> 4;
        const int d0 = (g & 15) * 4;
        float4 v = *(const float4*)&Qh[(size_t)(q0 + q) * DKH + d0];
        Qs[d0 + 0][q] = v.x; Qs[d0 + 1][q] = v.y;
        Qs[d0 + 2][q] = v.z; Qs[d0 + 3][q] = v.w;
    }

    float m_i[4], l_i[4], acc[4][4];
#pragma unroll
    for (int i = 0; i < 4; ++i) {
        m_i[i] = -1e30f; l_i[i] = 0.f;
#pragma unroll
        for (int j = 0; j < 4; ++j) acc[i][j] = 0.f;
    }

    for (int kt = 0; kt < L_SEQ; kt += 64) {
        // ---- stage K (transposed) + mask tile ----
#pragma unroll
        for (int c = 0; c < 4; ++c) {
            const int g  = t + 256 * c;
            const int k  = g >> 4;
            const int d0 = (g & 15) * 4;
            float4 v = *(const float4*)&Kh[(size_t)(kt + k) * DKH + d0];
            KVs[d0 + 0][k] = v.x; KVs[d0 + 1][k] = v.y;
            KVs[d0 + 2][k] = v.z; KVs[d0 + 3][k] = v.w;
        }
#pragma unroll
        for (int c = 0; c < 4; ++c) {
            const int g  = t + 256 * c;
            const int r  = g >> 4;
            const int c4 = (g & 15) * 4;
            int4 mv = *(const int4*)&mask[((size_t)b * L_SEQ + q0 + r) * L_SEQ + kt + c4];
            Msk[r][c4 + 0] = (unsigned char)(mv.x != 0);
            Msk[r][c4 + 1] = (unsigned char)(mv.y != 0);
            Msk[r][c4 + 2] = (unsigned char)(mv.z != 0);
            Msk[r][c4 + 3] = (unsigned char)(mv.w != 0);
        }
        __syncthreads();

        // ---- S = (Q K^T) / 8, then zero-fill mask ----
        float s[4][4];
#pragma unroll
        for (int i = 0; i < 4; ++i)
#pragma unroll
            for (int j = 0; j < 4; ++j) s[i][j] = 0.f;

#pragma unroll 16
        for (int d = 0; d < 64; ++d) {
            float4 af = *(const float4*)&Qs[d][ty * 4];
            float4 bf = *(const float4*)&KVs[d][tx * 4];
            float av[4] = {af.x, af.y, af.z, af.w};
            float bv[4] = {bf.x, bf.y, bf.z, bf.w};
#pragma unroll
            for (int i = 0; i < 4; ++i)
#pragma unroll
                for (int j = 0; j < 4; ++j)
                    s[i][j] = fmaf(av[i], bv[j], s[i][j]);
        }
#pragma unroll
        for (int i = 0; i < 4; ++i)
#pragma unroll
            for (int j = 0; j < 4; ++j) {
                const float sv = s[i][j] * 0.125f;
                s[i][j] = Msk[ty * 4 + i][tx * 4 + j] ? sv : 0.f;
            }
        __syncthreads();   // all reads of KVs-as-K and Msk complete

        // ---- stage V into KVs[k][d] (overwrites K) ----
#pragma unroll
        for (int c = 0; c < 4; ++c) {
            const int g  = t + 256 * c;
            const int k  = g >> 4;
            const int d0 = (g & 15) * 4;
            float4 v = *(const float4*)&Vh[(size_t)(kt + k) * DKH + d0];
            *(float4*)&KVs[k][d0] = v;
        }

        // ---- online softmax (masked entries keep s=0 -> exp(0-m)) ----
#pragma unroll
        for (int i = 0; i < 4; ++i) {
            float rm = fmaxf(fmaxf(s[i][0], s[i][1]), fmaxf(s[i][2], s[i][3]));
            rm = fmaxf(rm, __shfl_xor(rm, 1));
            rm = fmaxf(rm, __shfl_xor(rm, 2));
            rm = fmaxf(rm, __shfl_xor(rm, 4));
            rm = fmaxf(rm, __shfl_xor(rm, 8));
            const float m_new = fmaxf(m_i[i], rm);
            const float alpha = __expf(m_i[i] - m_new);
            const float p0 = __expf(s[i][0] - m_new);
            const float p1 = __expf(s[i][1] - m_new);
            const float p2 = __expf(s[i][2] - m_new);
            const float p3 = __expf(s[i][3] - m_new);
            float rs = p0 + p1 + p2 + p3;
            rs += __shfl_xor(rs, 1);
            rs += __shfl_xor(rs, 2);
            rs += __shfl_xor(rs, 4);
            rs += __shfl_xor(rs, 8);
            l_i[i] = l_i[i] * alpha + rs;
            m_i[i] = m_new;
            acc[i][0] *= alpha; acc[i][1] *= alpha;
            acc[i][2] *= alpha; acc[i][3] *= alpha;
            Ps[tx * 4 + 0][ty * 4 + i] = p0;
            Ps[tx * 4 + 1][ty * 4 + i] = p1;
            Ps[tx * 4 + 2][ty * 4 + i] = p2;
            Ps[tx * 4 + 3][ty * 4 + i] = p3;
        }
        __syncthreads();   // Ps and V visible

        // ---- O += P @ V ----
#pragma unroll 16
        for (int k = 0; k < 64; ++k) {
            float4 af = *(const float4*)&Ps[k][ty * 4];
            float4 bf = *(const float4*)&KVs[k][tx * 4];
            float av[4] = {af.x, af.y, af.z, af.w};
            float bv[4] = {bf.x, bf.y, bf.z, bf.w};
#pragma unroll
            for (int i = 0; i < 4; ++i)
#pragma unroll
                for (int j = 0; j < 4; ++j)
                    acc[i][j] = fmaf(av[i], bv[j], acc[i][j]);
        }
        __syncthreads();   // before next tile overwrites KVs/Msk/Ps
    }

    // epilogue: normalize, write O as [b][l][h*64+dk] (ready for O @ Wo)
#pragma unroll
    for (int i = 0; i < 4; ++i) {
        const float inv = 1.0f / l_i[i];
        const int q = q0 + ty * 4 + i;
        float4 o = make_float4(acc[i][0] * inv, acc[i][1] * inv,
                               acc[i][2] * inv, acc[i][3] * inv);
        *(float4*)&O[(size_t)(b * L_SEQ + q) * DMODEL + h * DKH + tx * 4] = o;
    }
}

// ---------------------------------------------------------------------------
extern "C" void kernel_launch(void* const* d_in, const int* in_sizes, int n_in,
                              void* d_out, int out_size, void* d_ws, size_t ws_size,
                              hipStream_t stream)
{
    (void)in_sizes; (void)n_in; (void)out_size; (void)ws_size;

    const float* Xq   = (const float*)d_in[0];
    const float* Xk   = (const float*)d_in[1];
    const float* Xv   = (const float*)d_in[2];
    const float* Wq   = (const float*)d_in[3];
    const float* Wk   = (const float*)d_in[4];
    const float* Wv   = (const float*)d_in[5];
    const float* Wo   = (const float*)d_in[6];
    const int*   mask = (const int*)d_in[7];
    float* out = (float*)d_out;

    const size_t tsz = (size_t)NB * NH * L_SEQ * DKH;  // 4,194,304 floats
    float* Qw = (float*)d_ws;
    float* Kw = Qw + tsz;
    float* Vw = Kw + tsz;
    float* Ow = Vw + tsz;   // [N,L,D] layout; total ws use = 64 MB

    dim3 gg(DMODEL / 128, (NB * L_SEQ) / 128, 1);   // (8, 32)
    gemm128<<<gg, 256, 0, stream>>>(Xq, Wq, Qw, 0);
    gemm128<<<gg, 256, 0, stream>>>(Xk, Wk, Kw, 0);
    gemm128<<<gg, 256, 0, stream>>>(Xv, Wv, Vw, 0);

    attn64<<<dim3(L_SEQ / 64, NH, NB), 256, 0, stream>>>(Qw, Kw, Vw, mask, Ow);

    gemm128<<<gg, 256, 0, stream>>>(Ow, Wo, out, 1);
}

// Round 2
// 792.636 us; speedup vs baseline: 1.7777x; 1.7777x over previous
//
#include <hip/hip_runtime.h>

#define NB 2
#define L_SEQ 2048
#define NH 16
#define DKH 64
#define DMODEL 1024
#define MROWS (NB * L_SEQ)          // 4096

typedef __attribute__((ext_vector_type(8))) short short8;
typedef __attribute__((ext_vector_type(4))) float f32x4;

static __device__ __forceinline__ unsigned short f2bf(float f) {
    unsigned u = __float_as_uint(f);
    u += 0x7fffu + ((u >> 16) & 1u);   // RTN-even
    return (unsigned short)(u >> 16);
}

static __device__ __forceinline__ void gll16(const void* g, void* l) {
    __builtin_amdgcn_global_load_lds(
        (const __attribute__((address_space(1))) void*)g,
        (__attribute__((address_space(3))) void*)l, 16, 0, 0);
}

// ---------------------------------------------------------------------------
// cast fp32 -> bf16, 3 sources selected by blockIdx.z, dst = base + z*4M elems
// ---------------------------------------------------------------------------
__global__ __launch_bounds__(256)
void cast3(const float* __restrict__ s0, const float* __restrict__ s1,
           const float* __restrict__ s2, unsigned short* __restrict__ dst)
{
    const int z = blockIdx.z;
    const float* src = (z == 0) ? s0 : (z == 1) ? s1 : s2;
    const size_t i4 = (size_t)blockIdx.x * 256 + threadIdx.x;   // float4 index
    float4 v = ((const float4*)src)[i4];
    ushort4 o;
    o.x = f2bf(v.x); o.y = f2bf(v.y); o.z = f2bf(v.z); o.w = f2bf(v.w);
    ((ushort4*)(dst + (size_t)z * 4194304))[i4] = o;
}

// ---------------------------------------------------------------------------
// cast + transpose W[1024][1024] fp32 -> Wt[n][k] bf16. z selects Wq/Wk/Wv/Wo.
// ---------------------------------------------------------------------------
__global__ __launch_bounds__(256)
void castWt(const float* __restrict__ w0, const float* __restrict__ w1,
            const float* __restrict__ w2, const float* __restrict__ w3,
            unsigned short* __restrict__ dst)
{
    __shared__ float ts[32][33];
    const int z = blockIdx.z;
    const float* W = (z == 0) ? w0 : (z == 1) ? w1 : (z == 2) ? w2 : w3;
    unsigned short* Wt = dst + (size_t)z * 1048576;

    const int k0 = blockIdx.y * 32;
    const int n0 = blockIdx.x * 32;
    const int t  = threadIdx.x;
    const int r  = t >> 3;
    const int c  = (t & 7) * 4;

    float4 v = *(const float4*)&W[(size_t)(k0 + r) * DMODEL + n0 + c];
    ts[r][c + 0] = v.x; ts[r][c + 1] = v.y; ts[r][c + 2] = v.z; ts[r][c + 3] = v.w;
    __syncthreads();

    ushort4 o;
    o.x = f2bf(ts[c + 0][r]); o.y = f2bf(ts[c + 1][r]);
    o.z = f2bf(ts[c + 2][r]); o.w = f2bf(ts[c + 3][r]);
    *(ushort4*)&Wt[(size_t)(n0 + r) * DMODEL + k0 + c] = o;
}

// ---------------------------------------------------------------------------
// bf16 MFMA GEMM (m97 structure): C[4096,1024] = A[4096,1024] @ Bt[1024,1024]^T
// BM=BN=128, BK=32, 256 threads = 4 waves (2x2 of 64x64), 16x16x32 mfma.
// global_load_lds width-16 staging; LDS tiles [128][32] bf16, k-contiguous.
// out_mode 0: scatter to [b][h][l][dk]; out_mode 1: row-major [row][col].
// z-strides let one launch cover Q/K/V.
// ---------------------------------------------------------------------------
__global__ __launch_bounds__(256)
void gemm_bf16(const unsigned short* __restrict__ Aall,
               const unsigned short* __restrict__ Ball,
               float* __restrict__ Oall,
               const int out_mode, const size_t a_zs, const size_t b_zs,
               const size_t o_zs)
{
    __shared__ __align__(16) unsigned short As[128 * 32];
    __shared__ __align__(16) unsigned short Bs[128 * 32];

    const int t    = threadIdx.x;
    const int w    = t >> 6;
    const int lane = t & 63;
    const int z    = blockIdx.z;
    const int m0   = blockIdx.y * 128;
    const int n0   = blockIdx.x * 128;

    const unsigned short* A = Aall + (size_t)z * a_zs;
    const unsigned short* B = Ball + (size_t)z * b_zs;
    float*                O = Oall + (size_t)z * o_zs;

    // staging: 512 16B-chunks per tile; wave w owns chunks [w*128, w*128+128)
    const int srow = w * 32 + (lane >> 2);        // tile row for inst 0
    const int skc  = (lane & 3) * 8;              // k offset (ushorts)
    const unsigned short* agp0 = A + (size_t)(m0 + srow) * DMODEL + skc;
    const unsigned short* agp1 = agp0 + (size_t)16 * DMODEL;
    const unsigned short* bgp0 = B + (size_t)(n0 + srow) * DMODEL + skc;
    const unsigned short* bgp1 = bgp0 + (size_t)16 * DMODEL;
    unsigned short* la0 = &As[w * 1024];
    unsigned short* la1 = la0 + 512;
    unsigned short* lb0 = &Bs[w * 1024];
    unsigned short* lb1 = lb0 + 512;

    const int ml = lane & 15;
    const int q  = lane >> 4;
    const int wm = (w >> 1) * 64;
    const int wn = (w & 1) * 64;

    const f32x4 z4 = {0.f, 0.f, 0.f, 0.f};
    f32x4 acc[4][4];
#pragma unroll
    for (int i = 0; i < 4; ++i)
#pragma unroll
        for (int j = 0; j < 4; ++j) acc[i][j] = z4;

    for (int kt = 0; kt < DMODEL; kt += 32) {
        __syncthreads();                      // prev tile's ds_reads done
        gll16(agp0 + kt, la0);
        gll16(agp1 + kt, la1);
        gll16(bgp0 + kt, lb0);
        gll16(bgp1 + kt, lb1);
        __syncthreads();                      // vmcnt(0) drained by barrier

        short8 av[4], bv[4];
#pragma unroll
        for (int mt = 0; mt < 4; ++mt)
            av[mt] = *(const short8*)&As[(wm + mt * 16 + ml) * 32 + q * 8];
#pragma unroll
        for (int nt = 0; nt < 4; ++nt)
            bv[nt] = *(const short8*)&Bs[(wn + nt * 16 + ml) * 32 + q * 8];
#pragma unroll
        for (int mt = 0; mt < 4; ++mt)
#pragma unroll
            for (int nt = 0; nt < 4; ++nt)
                acc[mt][nt] = __builtin_amdgcn_mfma_f32_16x16x32_bf16(
                    av[mt], bv[nt], acc[mt][nt], 0, 0, 0);
    }

    // C/D layout: col = lane&15, row = quad*4 + reg  [m89/m91 verified]
    if (out_mode == 0) {
#pragma unroll
        for (int mt = 0; mt < 4; ++mt) {
            const int gr0 = m0 + wm + mt * 16 + q * 4;
#pragma unroll
            for (int nt = 0; nt < 4; ++nt) {
                const int col = n0 + wn + nt * 16 + ml;
                const int hh  = col >> 6;
                const int dk  = col & (DKH - 1);
#pragma unroll
                for (int r = 0; r < 4; ++r) {
                    const int row = gr0 + r;
                    const int bb  = row >> 11;
                    const int l   = row & (L_SEQ - 1);
                    O[(((size_t)(bb * NH + hh) * L_SEQ + l) << 6) + dk] =
                        acc[mt][nt][r];
                }
            }
        }
    } else {
#pragma unroll
        for (int mt = 0; mt < 4; ++mt) {
            const int gr0 = m0 + wm + mt * 16 + q * 4;
#pragma unroll
            for (int nt = 0; nt < 4; ++nt) {
                const int col = n0 + wn + nt * 16 + ml;
#pragma unroll
                for (int r = 0; r < 4; ++r)
                    O[(size_t)(gr0 + r) * DMODEL + col] = acc[mt][nt][r];
            }
        }
    }
}

// ---------------------------------------------------------------------------
// Flash attention (fp32), zero-fill mask BEFORE softmax. Unchanged math from
// round 1 (verified); epilogue now emits bf16 O directly for the Wo GEMM.
// ---------------------------------------------------------------------------
__global__ __launch_bounds__(256)
void attn64(const float* __restrict__ Q, const float* __restrict__ K,
            const float* __restrict__ V, const int* __restrict__ mask,
            unsigned short* __restrict__ O)
{
    __shared__ float Qs [64][68];   // [d][q]
    __shared__ float KVs[64][68];   // K phase: [d][k];  V phase: [k][d]
    __shared__ float Ps [64][68];   // [k][q]
    __shared__ unsigned char Msk[64][64];

    const int t  = threadIdx.x;
    const int tx = t & 15;
    const int ty = t >> 4;
    const int b  = blockIdx.z;
    const int h  = blockIdx.y;
    const int q0 = blockIdx.x * 64;

    const size_t headoff = ((size_t)(b * NH + h)) * L_SEQ * DKH;
    const float* Qh = Q + headoff;
    const float* Kh = K + headoff;
    const float* Vh = V + headoff;

#pragma unroll
    for (int c = 0; c < 4; ++c) {
        const int g  = t + 256 * c;
        const int qq = g >> 4;
        const int d0 = (g & 15) * 4;
        float4 v = *(const float4*)&Qh[(size_t)(q0 + qq) * DKH + d0];
        Qs[d0 + 0][qq] = v.x; Qs[d0 + 1][qq] = v.y;
        Qs[d0 + 2][qq] = v.z; Qs[d0 + 3][qq] = v.w;
    }

    float m_i[4], l_i[4], acc[4][4];
#pragma unroll
    for (int i = 0; i < 4; ++i) {
        m_i[i] = -1e30f; l_i[i] = 0.f;
#pragma unroll
        for (int j = 0; j < 4; ++j) acc[i][j] = 0.f;
    }

    for (int kt = 0; kt < L_SEQ; kt += 64) {
#pragma unroll
        for (int c = 0; c < 4; ++c) {
            const int g  = t + 256 * c;
            const int k  = g >> 4;
            const int d0 = (g & 15) * 4;
            float4 v = *(const float4*)&Kh[(size_t)(kt + k) * DKH + d0];
            KVs[d0 + 0][k] = v.x; KVs[d0 + 1][k] = v.y;
            KVs[d0 + 2][k] = v.z; KVs[d0 + 3][k] = v.w;
        }
#pragma unroll
        for (int c = 0; c < 4; ++c) {
            const int g  = t + 256 * c;
            const int r  = g >> 4;
            const int c4 = (g & 15) * 4;
            int4 mv = *(const int4*)&mask[((size_t)b * L_SEQ + q0 + r) * L_SEQ + kt + c4];
            Msk[r][c4 + 0] = (unsigned char)(mv.x != 0);
            Msk[r][c4 + 1] = (unsigned char)(mv.y != 0);
            Msk[r][c4 + 2] = (unsigned char)(mv.z != 0);
            Msk[r][c4 + 3] = (unsigned char)(mv.w != 0);
        }
        __syncthreads();

        float s[4][4];
#pragma unroll
        for (int i = 0; i < 4; ++i)
#pragma unroll
            for (int j = 0; j < 4; ++j) s[i][j] = 0.f;

#pragma unroll 16
        for (int d = 0; d < 64; ++d) {
            float4 af = *(const float4*)&Qs[d][ty * 4];
            float4 bf = *(const float4*)&KVs[d][tx * 4];
            float av[4] = {af.x, af.y, af.z, af.w};
            float bv[4] = {bf.x, bf.y, bf.z, bf.w};
#pragma unroll
            for (int i = 0; i < 4; ++i)
#pragma unroll
                for (int j = 0; j < 4; ++j)
                    s[i][j] = fmaf(av[i], bv[j], s[i][j]);
        }
#pragma unroll
        for (int i = 0; i < 4; ++i)
#pragma unroll
            for (int j = 0; j < 4; ++j) {
                const float sv = s[i][j] * 0.125f;
                s[i][j] = Msk[ty * 4 + i][tx * 4 + j] ? sv : 0.f;
            }
        __syncthreads();

#pragma unroll
        for (int c = 0; c < 4; ++c) {
            const int g  = t + 256 * c;
            const int k  = g >> 4;
            const int d0 = (g & 15) * 4;
            float4 v = *(const float4*)&Vh[(size_t)(kt + k) * DKH + d0];
            *(float4*)&KVs[k][d0] = v;
        }

#pragma unroll
        for (int i = 0; i < 4; ++i) {
            float rm = fmaxf(fmaxf(s[i][0], s[i][1]), fmaxf(s[i][2], s[i][3]));
            rm = fmaxf(rm, __shfl_xor(rm, 1));
            rm = fmaxf(rm, __shfl_xor(rm, 2));
            rm = fmaxf(rm, __shfl_xor(rm, 4));
            rm = fmaxf(rm, __shfl_xor(rm, 8));
            const float m_new = fmaxf(m_i[i], rm);
            const float alpha = __expf(m_i[i] - m_new);
            const float p0 = __expf(s[i][0] - m_new);
            const float p1 = __expf(s[i][1] - m_new);
            const float p2 = __expf(s[i][2] - m_new);
            const float p3 = __expf(s[i][3] - m_new);
            float rs = p0 + p1 + p2 + p3;
            rs += __shfl_xor(rs, 1);
            rs += __shfl_xor(rs, 2);
            rs += __shfl_xor(rs, 4);
            rs += __shfl_xor(rs, 8);
            l_i[i] = l_i[i] * alpha + rs;
            m_i[i] = m_new;
            acc[i][0] *= alpha; acc[i][1] *= alpha;
            acc[i][2] *= alpha; acc[i][3] *= alpha;
            Ps[tx * 4 + 0][ty * 4 + i] = p0;
            Ps[tx * 4 + 1][ty * 4 + i] = p1;
            Ps[tx * 4 + 2][ty * 4 + i] = p2;
            Ps[tx * 4 + 3][ty * 4 + i] = p3;
        }
        __syncthreads();

#pragma unroll 16
        for (int k = 0; k < 64; ++k) {
            float4 af = *(const float4*)&Ps[k][ty * 4];
            float4 bf = *(const float4*)&KVs[k][tx * 4];
            float av[4] = {af.x, af.y, af.z, af.w};
            float bv[4] = {bf.x, bf.y, bf.z, bf.w};
#pragma unroll
            for (int i = 0; i < 4; ++i)
#pragma unroll
                for (int j = 0; j < 4; ++j)
                    acc[i][j] = fmaf(av[i], bv[j], acc[i][j]);
        }
        __syncthreads();
    }

    // epilogue: normalize + cast to bf16, layout [b][l][h*64+dk]
#pragma unroll
    for (int i = 0; i < 4; ++i) {
        const float inv = 1.0f / l_i[i];
        const int qq = q0 + ty * 4 + i;
        ushort4 o;
        o.x = f2bf(acc[i][0] * inv); o.y = f2bf(acc[i][1] * inv);
        o.z = f2bf(acc[i][2] * inv); o.w = f2bf(acc[i][3] * inv);
        *(ushort4*)&O[(size_t)(b * L_SEQ + qq) * DMODEL + h * DKH + tx * 4] = o;
    }
}

// ---------------------------------------------------------------------------
extern "C" void kernel_launch(void* const* d_in, const int* in_sizes, int n_in,
                              void* d_out, int out_size, void* d_ws, size_t ws_size,
                              hipStream_t stream)
{
    (void)in_sizes; (void)n_in; (void)out_size; (void)ws_size;

    const float* Xq   = (const float*)d_in[0];
    const float* Xk   = (const float*)d_in[1];
    const float* Xv   = (const float*)d_in[2];
    const float* Wq   = (const float*)d_in[3];
    const float* Wk   = (const float*)d_in[4];
    const float* Wv   = (const float*)d_in[5];
    const float* Wo   = (const float*)d_in[6];
    const int*   mask = (const int*)d_in[7];
    float* out = (float*)d_out;

    // workspace layout (88 MB total):
    //  [0,24MB)  XB   : Xq/Xk/Xv bf16, 3 x 4M ushort
    //  [24,32MB) WtB  : Wq/Wk/Wv/Wo transposed bf16, 4 x 1M ushort
    //  [32,80MB) QKV  : fp32 [b][h][l][dk], 3 x 4M float
    //  [80,88MB) OB   : attention output bf16 [b][l][d], 4M ushort
    char* base = (char*)d_ws;
    unsigned short* XB  = (unsigned short*)base;
    unsigned short* WtB = (unsigned short*)(base + (24u << 20));
    float*          QKV = (float*)(base + (32u << 20));
    unsigned short* OB  = (unsigned short*)(base + (80u << 20));

    const size_t tsz = (size_t)MROWS * DMODEL;   // 4,194,304

    cast3<<<dim3(4096, 1, 3), 256, 0, stream>>>(Xq, Xk, Xv, XB);
    castWt<<<dim3(32, 32, 4), 256, 0, stream>>>(Wq, Wk, Wv, Wo, WtB);

    // Q/K/V projections: one dispatch, z = 0/1/2, scatter to [b][h][l][dk]
    gemm_bf16<<<dim3(8, 32, 3), 256, 0, stream>>>(
        XB, WtB, QKV, 0, tsz, (size_t)DMODEL * DMODEL, tsz);

    attn64<<<dim3(L_SEQ / 64, NH, NB), 256, 0, stream>>>(
        QKV, QKV + tsz, QKV + 2 * tsz, mask, OB);

    // output projection: A = OB, W = Wo^T (4th slot), plain row-major out
    gemm_bf16<<<dim3(8, 32, 1), 256, 0, stream>>>(
        OB, WtB + 3 * (size_t)DMODEL * DMODEL, out, 1, 0, 0, 0);
}

// Round 3
// 325.024 us; speedup vs baseline: 4.3353x; 2.4387x over previous
//
#include <hip/hip_runtime.h>

#define NB 2
#define L_SEQ 2048
#define NH 16
#define DKH 64
#define DMODEL 1024
#define MROWS (NB * L_SEQ)          // 4096

typedef __attribute__((ext_vector_type(8))) short short8;
typedef __attribute__((ext_vector_type(4))) float f32x4;

static __device__ __forceinline__ unsigned short f2bf(float f) {
    unsigned u = __float_as_uint(f);
    u += 0x7fffu + ((u >> 16) & 1u);   // RTN-even
    return (unsigned short)(u >> 16);
}

static __device__ __forceinline__ void gll16(const void* g, void* l) {
    __builtin_amdgcn_global_load_lds(
        (const __attribute__((address_space(1))) void*)g,
        (__attribute__((address_space(3))) void*)l, 16, 0, 0);
}

// ---------------------------------------------------------------------------
// cast fp32 -> bf16, 3 sources selected by blockIdx.z
// ---------------------------------------------------------------------------
__global__ __launch_bounds__(256)
void cast3(const float* __restrict__ s0, const float* __restrict__ s1,
           const float* __restrict__ s2, unsigned short* __restrict__ dst)
{
    const int z = blockIdx.z;
    const float* src = (z == 0) ? s0 : (z == 1) ? s1 : s2;
    const size_t i4 = (size_t)blockIdx.x * 256 + threadIdx.x;
    float4 v = ((const float4*)src)[i4];
    ushort4 o;
    o.x = f2bf(v.x); o.y = f2bf(v.y); o.z = f2bf(v.z); o.w = f2bf(v.w);
    ((ushort4*)(dst + (size_t)z * 4194304))[i4] = o;
}

// ---------------------------------------------------------------------------
// cast + transpose W[1024][1024] fp32 -> Wt[n][k] bf16. z selects Wq/Wk/Wv/Wo.
// ---------------------------------------------------------------------------
__global__ __launch_bounds__(256)
void castWt(const float* __restrict__ w0, const float* __restrict__ w1,
            const float* __restrict__ w2, const float* __restrict__ w3,
            unsigned short* __restrict__ dst)
{
    __shared__ float ts[32][33];
    const int z = blockIdx.z;
    const float* W = (z == 0) ? w0 : (z == 1) ? w1 : (z == 2) ? w2 : w3;
    unsigned short* Wt = dst + (size_t)z * 1048576;

    const int k0 = blockIdx.y * 32;
    const int n0 = blockIdx.x * 32;
    const int t  = threadIdx.x;
    const int r  = t >> 3;
    const int c  = (t & 7) * 4;

    float4 v = *(const float4*)&W[(size_t)(k0 + r) * DMODEL + n0 + c];
    ts[r][c + 0] = v.x; ts[r][c + 1] = v.y; ts[r][c + 2] = v.z; ts[r][c + 3] = v.w;
    __syncthreads();

    ushort4 o;
    o.x = f2bf(ts[c + 0][r]); o.y = f2bf(ts[c + 1][r]);
    o.z = f2bf(ts[c + 2][r]); o.w = f2bf(ts[c + 3][r]);
    *(ushort4*)&Wt[(size_t)(n0 + r) * DMODEL + k0 + c] = o;
}

// ---------------------------------------------------------------------------
// mask int32 [N][L][L] -> bit-packed words, transposed layout:
// MWT[(b*32 + word)*L + row] = ballot(mask[b][row][word*64+lane] != 0)
// one wave produces one 64-bit word.
// ---------------------------------------------------------------------------
__global__ __launch_bounds__(256)
void maskbits(const int* __restrict__ mask, unsigned long long* __restrict__ MWT)
{
    const int lane = threadIdx.x & 63;
    const size_t wid = (size_t)blockIdx.x * 4 + (threadIdx.x >> 6);
    const int mv = mask[wid * 64 + lane];
    const unsigned long long bits = __ballot(mv != 0);
    if (lane == 0) {
        const int b   = (int)(wid >> 16);          // 2048*32 words per batch
        const int rem = (int)(wid & 65535);
        const int row = rem >> 5;
        const int wd  = rem & 31;
        MWT[((size_t)b * 32 + wd) * L_SEQ + row] = bits;
    }
}

// ---------------------------------------------------------------------------
// bf16 MFMA GEMM (m97 structure): C[4096,1024] = A @ Bt^T
// out_mode 0: bf16 out; z=0/1 -> Q/K [b][h][l][dk]; z=2 -> V^T [b][h][dk][l]
// out_mode 1: fp32 row-major [row][col] (final output)
// ---------------------------------------------------------------------------
__global__ __launch_bounds__(256)
void gemm_bf16(const unsigned short* __restrict__ Aall,
               const unsigned short* __restrict__ Ball,
               void* __restrict__ Oall,
               const int out_mode, const size_t a_zs, const size_t b_zs,
               const size_t o_zs)
{
    __shared__ __align__(16) unsigned short As[128 * 32];
    __shared__ __align__(16) unsigned short Bs[128 * 32];

    const int t    = threadIdx.x;
    const int w    = t >> 6;
    const int lane = t & 63;
    const int z    = blockIdx.z;
    const int m0   = blockIdx.y * 128;
    const int n0   = blockIdx.x * 128;

    const unsigned short* A = Aall + (size_t)z * a_zs;
    const unsigned short* B = Ball + (size_t)z * b_zs;

    const int srow = w * 32 + (lane >> 2);
    const int skc  = (lane & 3) * 8;
    const unsigned short* agp0 = A + (size_t)(m0 + srow) * DMODEL + skc;
    const unsigned short* agp1 = agp0 + (size_t)16 * DMODEL;
    const unsigned short* bgp0 = B + (size_t)(n0 + srow) * DMODEL + skc;
    const unsigned short* bgp1 = bgp0 + (size_t)16 * DMODEL;
    unsigned short* la0 = &As[w * 1024];
    unsigned short* la1 = la0 + 512;
    unsigned short* lb0 = &Bs[w * 1024];
    unsigned short* lb1 = lb0 + 512;

    const int ml = lane & 15;
    const int q  = lane >> 4;
    const int wm = (w >> 1) * 64;
    const int wn = (w & 1) * 64;

    const f32x4 z4 = {0.f, 0.f, 0.f, 0.f};
    f32x4 acc[4][4];
#pragma unroll
    for (int i = 0; i < 4; ++i)
#pragma unroll
        for (int j = 0; j < 4; ++j) acc[i][j] = z4;

    for (int kt = 0; kt < DMODEL; kt += 32) {
        __syncthreads();
        gll16(agp0 + kt, la0);
        gll16(agp1 + kt, la1);
        gll16(bgp0 + kt, lb0);
        gll16(bgp1 + kt, lb1);
        __syncthreads();

        short8 av[4], bv[4];
#pragma unroll
        for (int mt = 0; mt < 4; ++mt)
            av[mt] = *(const short8*)&As[(wm + mt * 16 + ml) * 32 + q * 8];
#pragma unroll
        for (int nt = 0; nt < 4; ++nt)
            bv[nt] = *(const short8*)&Bs[(wn + nt * 16 + ml) * 32 + q * 8];
#pragma unroll
        for (int mt = 0; mt < 4; ++mt)
#pragma unroll
            for (int nt = 0; nt < 4; ++nt)
                acc[mt][nt] = __builtin_amdgcn_mfma_f32_16x16x32_bf16(
                    av[mt], bv[nt], acc[mt][nt], 0, 0, 0);
    }

    // C/D layout: col = lane&15, row = quad*4 + reg
    if (out_mode == 0) {
        unsigned short* O = (unsigned short*)Oall + (size_t)z * o_zs;
#pragma unroll
        for (int mt = 0; mt < 4; ++mt) {
            const int gr0 = m0 + wm + mt * 16 + q * 4;
#pragma unroll
            for (int nt = 0; nt < 4; ++nt) {
                const int col = n0 + wn + nt * 16 + ml;
                const int hh  = col >> 6;
                const int dk  = col & (DKH - 1);
#pragma unroll
                for (int r = 0; r < 4; ++r) {
                    const int row = gr0 + r;
                    const int bb  = row >> 11;
                    const int l   = row & (L_SEQ - 1);
                    if (z == 2)   // V^T: [b][h][dk][l]
                        O[((size_t)(bb * NH + hh) * DKH + dk) * L_SEQ + l] =
                            f2bf(acc[mt][nt][r]);
                    else          // Q/K: [b][h][l][dk]
                        O[(((size_t)(bb * NH + hh) * L_SEQ + l) << 6) + dk] =
                            f2bf(acc[mt][nt][r]);
                }
            }
        }
    } else {
        float* O = (float*)Oall;
#pragma unroll
        for (int mt = 0; mt < 4; ++mt) {
            const int gr0 = m0 + wm + mt * 16 + q * 4;
#pragma unroll
            for (int nt = 0; nt < 4; ++nt) {
                const int col = n0 + wn + nt * 16 + ml;
#pragma unroll
                for (int r = 0; r < 4; ++r)
                    O[(size_t)(gr0 + r) * DMODEL + col] = acc[mt][nt][r];
            }
        }
    }
}

// ---------------------------------------------------------------------------
// MFMA flash attention, zero-fill mask before softmax.
// Block = (128 q-rows, head, batch), 4 waves; wave owns 32 q-rows.
// Computes S^T = K@Q^T and O^T = V^T@P^T so row stats live on col=lane&15:
// only shfl_xor(16,32) reductions, alpha ownership matches O layout, and P
// is produced in [q][k] with 4 k-consecutive regs -> ds_write_b64.
// All LDS tiles: [row][128B] with 16B-chunk XOR swizzle chunk^=(row&7);
// global_load_lds per-lane src addresses implement the swizzle for free.
// ---------------------------------------------------------------------------
__global__ __launch_bounds__(256, 2)
void attn_mfma(const unsigned short* __restrict__ Qb,
               const unsigned short* __restrict__ Kb,
               const unsigned short* __restrict__ Vtb,
               const unsigned long long* __restrict__ MWT,
               unsigned short* __restrict__ OB)
{
    __shared__ __align__(16) unsigned short Qs[128 * 64];   // [q][d] swizzled
    __shared__ __align__(16) unsigned short Ks[64 * 64];    // [k][d] swizzled
    __shared__ __align__(16) unsigned short Vts[64 * 64];   // [d][k] swizzled
    __shared__ __align__(16) unsigned short Ps[4][32 * 64]; // per-wave [q][k]
    __shared__ __align__(16) unsigned long long MskL[128];  // word per q-row

    const int t    = threadIdx.x;
    const int w    = t >> 6;
    const int lane = t & 63;
    const int ml   = lane & 15;
    const int quad = lane >> 4;

    const int q0 = blockIdx.x * 128;
    const int h  = blockIdx.y;
    const int b  = blockIdx.z;

    const size_t hoff = (size_t)(b * NH + h) * L_SEQ * DKH;
    const unsigned short* Qh  = Qb  + hoff;
    const unsigned short* Kh  = Kb  + hoff;
    const unsigned short* Vth = Vtb + hoff;     // [64][L_SEQ]

    // staging lane constants: row-in-8 and swizzled chunk col
    const int srow = lane >> 3;                 // 0..7
    const int sc   = (lane & 7) ^ srow;         // chunk' = chunk ^ (row&7)

    // ---- stage Q once (4 gll16 per wave) ----
#pragma unroll
    for (int j = 0; j < 4; ++j) {
        const int R0 = w * 32 + j * 8;
        gll16(Qh + (size_t)(q0 + R0 + srow) * DKH + sc * 8, &Qs[R0 * 64]);
    }
    __syncthreads();

    // Q B-frags, loop-invariant: qf[qt][s]
    short8 qf[2][2];
#pragma unroll
    for (int qt = 0; qt < 2; ++qt)
#pragma unroll
        for (int s = 0; s < 2; ++s)
            qf[qt][s] = *(const short8*)
                &Qs[(w * 32 + qt * 16 + ml) * 64 + (((s * 4 + quad) ^ (ml & 7)) * 8)];

    // K/V staging pointers (advance per iteration)
    const unsigned short* kg0 = Kh + (size_t)(w * 16 + srow) * DKH + sc * 8;
    const unsigned short* kg1 = Kh + (size_t)(w * 16 + 8 + srow) * DKH + sc * 8;
    const unsigned short* vg0 = Vth + (size_t)(w * 16 + srow) * L_SEQ + sc * 8;
    const unsigned short* vg1 = Vth + (size_t)(w * 16 + 8 + srow) * L_SEQ + sc * 8;
    unsigned short* lk0 = &Ks[(w * 16) * 64];
    unsigned short* lk1 = &Ks[(w * 16 + 8) * 64];
    unsigned short* lv0 = &Vts[(w * 16) * 64];
    unsigned short* lv1 = &Vts[(w * 16 + 8) * 64];
    const unsigned long long* mg = MWT + (size_t)b * 32 * L_SEQ + q0 + t;

    f32x4 oacc[4][2];            // [dt][qt]  (O^T: row=d, col=q)
    const f32x4 z4 = {0.f, 0.f, 0.f, 0.f};
#pragma unroll
    for (int dt = 0; dt < 4; ++dt)
#pragma unroll
        for (int qt = 0; qt < 2; ++qt) oacc[dt][qt] = z4;
    float m_i[2] = {-1e30f, -1e30f};
    float l_i[2] = {0.f, 0.f};

    for (int j = 0; j < 32; ++j) {
        __syncthreads();                       // prev iter's tile reads done
        gll16(kg0, lk0);  gll16(kg1, lk1);
        gll16(vg0, lv0);  gll16(vg1, lv1);
        kg0 += 64 * DKH;  kg1 += 64 * DKH;     // next 64 K rows
        vg0 += 64;        vg1 += 64;           // next 64 cols of V^T
        unsigned long long mw_val = 0;
        if (t < 128) mw_val = mg[(size_t)j * L_SEQ];
        if (t < 128) MskL[t] = mw_val;
        __syncthreads();                       // staging drained

        // ---- S^T = K @ Q^T : sacc[kt][qt], row=k-col, col=q ----
        f32x4 sacc[4][2];
#pragma unroll
        for (int kt = 0; kt < 4; ++kt)
#pragma unroll
            for (int qt = 0; qt < 2; ++qt) sacc[kt][qt] = z4;
#pragma unroll
        for (int s = 0; s < 2; ++s) {
            short8 kf[4];
#pragma unroll
            for (int kt = 0; kt < 4; ++kt)
                kf[kt] = *(const short8*)
                    &Ks[(kt * 16 + ml) * 64 + (((s * 4 + quad) ^ (ml & 7)) * 8)];
#pragma unroll
            for (int kt = 0; kt < 4; ++kt)
#pragma unroll
                for (int qt = 0; qt < 2; ++qt)
                    sacc[kt][qt] = __builtin_amdgcn_mfma_f32_16x16x32_bf16(
                        kf[kt], qf[qt][s], sacc[kt][qt], 0, 0, 0);
        }

        // ---- mask + scale + online softmax (per qt; rows on ml lanes) ----
#pragma unroll
        for (int qt = 0; qt < 2; ++qt) {
            const unsigned long long wq =
                MskL[w * 32 + qt * 16 + ml] >> (quad * 4);
            float sm[4][4];                    // [kt][r], k = kt*16+quad*4+r
#pragma unroll
            for (int kt = 0; kt < 4; ++kt)
#pragma unroll
                for (int r = 0; r < 4; ++r) {
                    const bool bit = (wq >> (kt * 16 + r)) & 1ull;
                    sm[kt][r] = bit ? sacc[kt][qt][r] * 0.125f : 0.f;
                }
            float rm = sm[0][0];
#pragma unroll
            for (int kt = 0; kt < 4; ++kt)
#pragma unroll
                for (int r = 0; r < 4; ++r) rm = fmaxf(rm, sm[kt][r]);
            rm = fmaxf(rm, __shfl_xor(rm, 16));
            rm = fmaxf(rm, __shfl_xor(rm, 32));
            const float mn = fmaxf(m_i[qt], rm);
            const float al = __expf(m_i[qt] - mn);
            float p[4][4];
            float rs = 0.f;
#pragma unroll
            for (int kt = 0; kt < 4; ++kt)
#pragma unroll
                for (int r = 0; r < 4; ++r) {
                    p[kt][r] = __expf(sm[kt][r] - mn);
                    rs += p[kt][r];
                }
            rs += __shfl_xor(rs, 16);
            rs += __shfl_xor(rs, 32);
            l_i[qt] = l_i[qt] * al + rs;
            m_i[qt] = mn;
#pragma unroll
            for (int dt = 0; dt < 4; ++dt) oacc[dt][qt] *= al;
            // write P[q][k] packed: 4 k-consecutive -> b64, swizzled chunk
#pragma unroll
            for (int kt = 0; kt < 4; ++kt) {
                ushort4 pk;
                pk.x = f2bf(p[kt][0]); pk.y = f2bf(p[kt][1]);
                pk.z = f2bf(p[kt][2]); pk.w = f2bf(p[kt][3]);
                const int cp = (kt * 2 + (quad >> 1)) ^ (ml & 7);
                *(ushort4*)&Ps[w][(qt * 16 + ml) * 64 + cp * 8 + (quad & 1) * 4] = pk;
            }
        }
        // own-wave P write->read: compiler lgkmcnt handles; Vts synced above.

        // ---- O^T += V^T @ P^T : oacc[dt][qt] ----
#pragma unroll
        for (int s = 0; s < 2; ++s) {
            short8 pf[2];
#pragma unroll
            for (int qt = 0; qt < 2; ++qt)
                pf[qt] = *(const short8*)
                    &Ps[w][(qt * 16 + ml) * 64 + (((s * 4 + quad) ^ (ml & 7)) * 8)];
#pragma unroll
            for (int dt = 0; dt < 4; ++dt) {
                const short8 vf = *(const short8*)
                    &Vts[(dt * 16 + ml) * 64 + (((s * 4 + quad) ^ (ml & 7)) * 8)];
#pragma unroll
                for (int qt = 0; qt < 2; ++qt)
                    oacc[dt][qt] = __builtin_amdgcn_mfma_f32_16x16x32_bf16(
                        vf, pf[qt], oacc[dt][qt], 0, 0, 0);
            }
        }
    }

    // ---- epilogue: O^T C-layout row=d=quad*4+r(+16dt), col=q=ml(+16qt) ----
    const float inv0 = 1.0f / l_i[0];
    const float inv1 = 1.0f / l_i[1];
#pragma unroll
    for (int dt = 0; dt < 4; ++dt)
#pragma unroll
        for (int r = 0; r < 4; ++r) {
            const int d = dt * 16 + quad * 4 + r;
#pragma unroll
            for (int qt = 0; qt < 2; ++qt) {
                const int qrow = q0 + w * 32 + qt * 16 + ml;
                OB[(size_t)(b * L_SEQ + qrow) * DMODEL + h * DKH + d] =
                    f2bf(oacc[dt][qt][r] * (qt ? inv1 : inv0));
            }
        }
}

// ---------------------------------------------------------------------------
extern "C" void kernel_launch(void* const* d_in, const int* in_sizes, int n_in,
                              void* d_out, int out_size, void* d_ws, size_t ws_size,
                              hipStream_t stream)
{
    (void)in_sizes; (void)n_in; (void)out_size; (void)ws_size;

    const float* Xq   = (const float*)d_in[0];
    const float* Xk   = (const float*)d_in[1];
    const float* Xv   = (const float*)d_in[2];
    const float* Wq   = (const float*)d_in[3];
    const float* Wk   = (const float*)d_in[4];
    const float* Wv   = (const float*)d_in[5];
    const float* Wo   = (const float*)d_in[6];
    const int*   mask = (const int*)d_in[7];
    float* out = (float*)d_out;

    // ws layout (65 MB):
    //  [0,24)   XB  : Xq/Xk/Xv bf16
    //  [24,32)  WtB : W^T bf16 x4
    //  [32,56)  QKV : Q,K [b][h][l][dk] bf16; V^T [b][h][dk][l] bf16
    //  [56,64)  OB  : attention out bf16 [b][l][d]
    //  [64,65)  MWT : bit-packed mask words, [b][word][row]
    char* base = (char*)d_ws;
    unsigned short*     XB  = (unsigned short*)base;
    unsigned short*     WtB = (unsigned short*)(base + (24u << 20));
    unsigned short*     QKV = (unsigned short*)(base + (32u << 20));
    unsigned short*     OB  = (unsigned short*)(base + (56u << 20));
    unsigned long long* MWT = (unsigned long long*)(base + (64u << 20));

    const size_t tsz = (size_t)MROWS * DMODEL;   // 4,194,304

    cast3<<<dim3(4096, 1, 3), 256, 0, stream>>>(Xq, Xk, Xv, XB);
    castWt<<<dim3(32, 32, 4), 256, 0, stream>>>(Wq, Wk, Wv, Wo, WtB);
    maskbits<<<dim3(32768), 256, 0, stream>>>(mask, MWT);

    gemm_bf16<<<dim3(8, 32, 3), 256, 0, stream>>>(
        XB, WtB, (void*)QKV, 0, tsz, (size_t)DMODEL * DMODEL, tsz);

    attn_mfma<<<dim3(L_SEQ / 128, NH, NB), 256, 0, stream>>>(
        QKV, QKV + tsz, QKV + 2 * tsz, MWT, OB);

    gemm_bf16<<<dim3(8, 32, 1), 256, 0, stream>>>(
        OB, WtB + 3 * (size_t)DMODEL * DMODEL, (void*)out, 1, 0, 0, 0);
}

// Round 4
// 297.873 us; speedup vs baseline: 4.7305x; 1.0912x over previous
//
#include <hip/hip_runtime.h>

#define NB 2
#define L_SEQ 2048
#define NH 16
#define DKH 64
#define DMODEL 1024
#define MROWS (NB * L_SEQ)          // 4096

typedef __attribute__((ext_vector_type(8))) short short8;
typedef __attribute__((ext_vector_type(4))) float f32x4;

static __device__ __forceinline__ unsigned short f2bf(float f) {
    unsigned u = __float_as_uint(f);
    u += 0x7fffu + ((u >> 16) & 1u);   // RTN-even
    return (unsigned short)(u >> 16);
}

static __device__ __forceinline__ float fexp2(float x) {
#if __has_builtin(__builtin_amdgcn_exp2f)
    return __builtin_amdgcn_exp2f(x);
#else
    return __expf(x * 0.6931471806f);
#endif
}

static __device__ __forceinline__ void gll16(const void* g, void* l) {
    __builtin_amdgcn_global_load_lds(
        (const __attribute__((address_space(1))) void*)g,
        (__attribute__((address_space(3))) void*)l, 16, 0, 0);
}

// ---------------------------------------------------------------------------
// cast fp32 -> bf16, 3 sources selected by blockIdx.z
// ---------------------------------------------------------------------------
__global__ __launch_bounds__(256)
void cast3(const float* __restrict__ s0, const float* __restrict__ s1,
           const float* __restrict__ s2, unsigned short* __restrict__ dst)
{
    const int z = blockIdx.z;
    const float* src = (z == 0) ? s0 : (z == 1) ? s1 : s2;
    const size_t i4 = (size_t)blockIdx.x * 256 + threadIdx.x;
    float4 v = ((const float4*)src)[i4];
    ushort4 o;
    o.x = f2bf(v.x); o.y = f2bf(v.y); o.z = f2bf(v.z); o.w = f2bf(v.w);
    ((ushort4*)(dst + (size_t)z * 4194304))[i4] = o;
}

// ---------------------------------------------------------------------------
// cast + transpose W[1024][1024] fp32 -> Wt[n][k] bf16. z selects Wq/Wk/Wv/Wo.
// ---------------------------------------------------------------------------
__global__ __launch_bounds__(256)
void castWt(const float* __restrict__ w0, const float* __restrict__ w1,
            const float* __restrict__ w2, const float* __restrict__ w3,
            unsigned short* __restrict__ dst)
{
    __shared__ float ts[32][33];
    const int z = blockIdx.z;
    const float* W = (z == 0) ? w0 : (z == 1) ? w1 : (z == 2) ? w2 : w3;
    unsigned short* Wt = dst + (size_t)z * 1048576;

    const int k0 = blockIdx.y * 32;
    const int n0 = blockIdx.x * 32;
    const int t  = threadIdx.x;
    const int r  = t >> 3;
    const int c  = (t & 7) * 4;

    float4 v = *(const float4*)&W[(size_t)(k0 + r) * DMODEL + n0 + c];
    ts[r][c + 0] = v.x; ts[r][c + 1] = v.y; ts[r][c + 2] = v.z; ts[r][c + 3] = v.w;
    __syncthreads();

    ushort4 o;
    o.x = f2bf(ts[c + 0][r]); o.y = f2bf(ts[c + 1][r]);
    o.z = f2bf(ts[c + 2][r]); o.w = f2bf(ts[c + 3][r]);
    *(ushort4*)&Wt[(size_t)(n0 + r) * DMODEL + k0 + c] = o;
}

// ---------------------------------------------------------------------------
// mask int32 [N][L][L] -> bit-packed words, transposed layout:
// MWT[(b*32 + word)*L + row] = ballot(mask[b][row][word*64+lane] != 0)
// ---------------------------------------------------------------------------
__global__ __launch_bounds__(256)
void maskbits(const int* __restrict__ mask, unsigned long long* __restrict__ MWT)
{
    const int lane = threadIdx.x & 63;
    const size_t wid = (size_t)blockIdx.x * 4 + (threadIdx.x >> 6);
    const int mv = mask[wid * 64 + lane];
    const unsigned long long bits = __ballot(mv != 0);
    if (lane == 0) {
        const int b   = (int)(wid >> 16);
        const int rem = (int)(wid & 65535);
        const int row = rem >> 5;
        const int wd  = rem & 31;
        MWT[((size_t)b * 32 + wd) * L_SEQ + row] = bits;
    }
}

// ---------------------------------------------------------------------------
// bf16 MFMA GEMM (m97 structure): C[4096,1024] = A @ Bt^T
// out_mode 0: bf16 out; z=0/1 -> Q/K [b][h][l][dk] (scalar stores);
//             z=2 -> V^T [b][h][dk][l] via LDS-transpose, 16B coalesced stores
// out_mode 1: fp32 row-major (final output)
// ---------------------------------------------------------------------------
__global__ __launch_bounds__(256)
void gemm_bf16(const unsigned short* __restrict__ Aall,
               const unsigned short* __restrict__ Ball,
               void* __restrict__ Oall,
               const int out_mode, const size_t a_zs, const size_t b_zs,
               const size_t o_zs)
{
    __shared__ __align__(16) unsigned short As[128 * 32];
    __shared__ __align__(16) unsigned short Bs[128 * 32];
    __shared__ __align__(16) unsigned short Ts[128 * 128];  // z==2 transpose

    const int t    = threadIdx.x;
    const int w    = t >> 6;
    const int lane = t & 63;
    const int z    = blockIdx.z;
    const int m0   = blockIdx.y * 128;
    const int n0   = blockIdx.x * 128;

    const unsigned short* A = Aall + (size_t)z * a_zs;
    const unsigned short* B = Ball + (size_t)z * b_zs;

    const int srow = w * 32 + (lane >> 2);
    const int skc  = (lane & 3) * 8;
    const unsigned short* agp0 = A + (size_t)(m0 + srow) * DMODEL + skc;
    const unsigned short* agp1 = agp0 + (size_t)16 * DMODEL;
    const unsigned short* bgp0 = B + (size_t)(n0 + srow) * DMODEL + skc;
    const unsigned short* bgp1 = bgp0 + (size_t)16 * DMODEL;
    unsigned short* la0 = &As[w * 1024];
    unsigned short* la1 = la0 + 512;
    unsigned short* lb0 = &Bs[w * 1024];
    unsigned short* lb1 = lb0 + 512;

    const int ml = lane & 15;
    const int q  = lane >> 4;
    const int wm = (w >> 1) * 64;
    const int wn = (w & 1) * 64;

    const f32x4 z4 = {0.f, 0.f, 0.f, 0.f};
    f32x4 acc[4][4];
#pragma unroll
    for (int i = 0; i < 4; ++i)
#pragma unroll
        for (int j = 0; j < 4; ++j) acc[i][j] = z4;

    for (int kt = 0; kt < DMODEL; kt += 32) {
        __syncthreads();
        gll16(agp0 + kt, la0);
        gll16(agp1 + kt, la1);
        gll16(bgp0 + kt, lb0);
        gll16(bgp1 + kt, lb1);
        __syncthreads();

        short8 av[4], bv[4];
#pragma unroll
        for (int mt = 0; mt < 4; ++mt)
            av[mt] = *(const short8*)&As[(wm + mt * 16 + ml) * 32 + q * 8];
#pragma unroll
        for (int nt = 0; nt < 4; ++nt)
            bv[nt] = *(const short8*)&Bs[(wn + nt * 16 + ml) * 32 + q * 8];
#pragma unroll
        for (int mt = 0; mt < 4; ++mt)
#pragma unroll
            for (int nt = 0; nt < 4; ++nt)
                acc[mt][nt] = __builtin_amdgcn_mfma_f32_16x16x32_bf16(
                    av[mt], bv[nt], acc[mt][nt], 0, 0, 0);
    }

    // C/D layout: col = lane&15, row = quad*4 + reg
    if (out_mode == 0) {
        unsigned short* O = (unsigned short*)Oall + (size_t)z * o_zs;
        if (z == 2) {
            // ---- V^T: stage C-tile transposed in LDS, store wide ----
            // Ts logical [tcol=n][trow=m], 16 chunks of 8 ushorts per row,
            // physical chunk pc = (c&8) | ((c&7) ^ (tcol&7))
#pragma unroll
            for (int mt = 0; mt < 4; ++mt) {
                const int trow0 = wm + mt * 16 + q * 4;
                const int ch    = trow0 >> 3;
#pragma unroll
                for (int nt = 0; nt < 4; ++nt) {
                    const int tcol = wn + nt * 16 + ml;
                    const int pc   = (ch & 8) | ((ch & 7) ^ (tcol & 7));
                    ushort4 pv;
                    pv.x = f2bf(acc[mt][nt][0]); pv.y = f2bf(acc[mt][nt][1]);
                    pv.z = f2bf(acc[mt][nt][2]); pv.w = f2bf(acc[mt][nt][3]);
                    *(ushort4*)&Ts[tcol * 128 + pc * 8 + (trow0 & 7)] = pv;
                }
            }
            __syncthreads();
            const int bb = m0 >> 11;
            const int l0 = (m0 & (L_SEQ - 1)) + (t & 15) * 8;
            const int cr = t & 15;
#pragma unroll
            for (int it = 0; it < 8; ++it) {
                const int tcol = (t >> 4) + 16 * it;
                const int pc   = (cr & 8) | ((cr & 7) ^ (tcol & 7));
                short8 vv = *(const short8*)&Ts[tcol * 128 + pc * 8];
                const int n  = n0 + tcol;
                const int hh = n >> 6;
                const int dk = n & (DKH - 1);
                *(short8*)&O[((size_t)(bb * NH + hh) * DKH + dk) * L_SEQ + l0] = vv;
            }
        } else {
            // Q/K: [b][h][l][dk]
#pragma unroll
            for (int mt = 0; mt < 4; ++mt) {
                const int gr0 = m0 + wm + mt * 16 + q * 4;
#pragma unroll
                for (int nt = 0; nt < 4; ++nt) {
                    const int col = n0 + wn + nt * 16 + ml;
                    const int hh  = col >> 6;
                    const int dk  = col & (DKH - 1);
#pragma unroll
                    for (int r = 0; r < 4; ++r) {
                        const int row = gr0 + r;
                        const int bb  = row >> 11;
                        const int l   = row & (L_SEQ - 1);
                        O[(((size_t)(bb * NH + hh) * L_SEQ + l) << 6) + dk] =
                            f2bf(acc[mt][nt][r]);
                    }
                }
            }
        }
    } else {
        float* O = (float*)Oall;
#pragma unroll
        for (int mt = 0; mt < 4; ++mt) {
            const int gr0 = m0 + wm + mt * 16 + q * 4;
#pragma unroll
            for (int nt = 0; nt < 4; ++nt) {
                const int col = n0 + wn + nt * 16 + ml;
#pragma unroll
                for (int r = 0; r < 4; ++r)
                    O[(size_t)(gr0 + r) * DMODEL + col] = acc[mt][nt][r];
            }
        }
    }
}

// ---------------------------------------------------------------------------
// MFMA flash attention, zero-fill mask before softmax, NO online max
// (scores bounded; exp cannot overflow fp32). Block = 64 q-rows, 4 waves,
// wave owns 16 q. S^T = K@Q^T, O^T = V^T@P^T (row stats on col=lane&15 ->
// only shfl 16/32 for the sum; no cross-lane alpha since max is constant).
// 1024 blocks = 4 blocks/CU = 16 waves/CU. Mask word prefetched one iter
// ahead so its global latency overlaps compute.
// ---------------------------------------------------------------------------
__global__ __launch_bounds__(256, 4)
void attn_mfma(const unsigned short* __restrict__ Qb,
               const unsigned short* __restrict__ Kb,
               const unsigned short* __restrict__ Vtb,
               const unsigned long long* __restrict__ MWT,
               unsigned short* __restrict__ OB)
{
    __shared__ __align__(16) unsigned short Qs[64 * 64];
    __shared__ __align__(16) unsigned short Ks[64 * 64];
    __shared__ __align__(16) unsigned short Vts[64 * 64];
    __shared__ __align__(16) unsigned short Ps[4][16 * 64];
    __shared__ __align__(16) unsigned long long MskL[64];

    const int t    = threadIdx.x;
    const int w    = t >> 6;
    const int lane = t & 63;
    const int ml   = lane & 15;
    const int quad = lane >> 4;

    const int q0 = blockIdx.x * 64;
    const int h  = blockIdx.y;
    const int b  = blockIdx.z;

    const size_t hoff = (size_t)(b * NH + h) * L_SEQ * DKH;
    const unsigned short* Qh  = Qb  + hoff;
    const unsigned short* Kh  = Kb  + hoff;
    const unsigned short* Vth = Vtb + hoff;     // [64][L_SEQ]

    const int srow = lane >> 3;                 // 0..7
    const int sc   = (lane & 7) ^ srow;         // swizzled source chunk

    // ---- stage Q (2 gll16 per wave) ----
    gll16(Qh + (size_t)(q0 + w * 16 + srow) * DKH + sc * 8, &Qs[(w * 16) * 64]);
    gll16(Qh + (size_t)(q0 + w * 16 + 8 + srow) * DKH + sc * 8, &Qs[(w * 16 + 8) * 64]);
    __syncthreads();

    short8 qf[2];
#pragma unroll
    for (int s = 0; s < 2; ++s)
        qf[s] = *(const short8*)
            &Qs[(w * 16 + ml) * 64 + (((s * 4 + quad) ^ (ml & 7)) * 8)];

    const unsigned short* kg0 = Kh + (size_t)(w * 16 + srow) * DKH + sc * 8;
    const unsigned short* kg1 = Kh + (size_t)(w * 16 + 8 + srow) * DKH + sc * 8;
    const unsigned short* vg0 = Vth + (size_t)(w * 16 + srow) * L_SEQ + sc * 8;
    const unsigned short* vg1 = Vth + (size_t)(w * 16 + 8 + srow) * L_SEQ + sc * 8;
    unsigned short* lk0 = &Ks[(w * 16) * 64];
    unsigned short* lk1 = &Ks[(w * 16 + 8) * 64];
    unsigned short* lv0 = &Vts[(w * 16) * 64];
    unsigned short* lv1 = &Vts[(w * 16 + 8) * 64];

    const unsigned long long* mg = MWT + (size_t)b * 32 * L_SEQ + q0 + t;
    unsigned long long m_pf = 0;
    if (t < 64) m_pf = mg[0];

    f32x4 oacc[4];
    const f32x4 z4 = {0.f, 0.f, 0.f, 0.f};
#pragma unroll
    for (int dt = 0; dt < 4; ++dt) oacc[dt] = z4;
    float l_i = 0.f;

    for (int j = 0; j < 32; ++j) {
        __syncthreads();                       // prev iter's tile reads done
        gll16(kg0, lk0);  gll16(kg1, lk1);
        gll16(vg0, lv0);  gll16(vg1, lv1);
        kg0 += 64 * DKH;  kg1 += 64 * DKH;
        vg0 += 64;        vg1 += 64;
        if (t < 64) {
            MskL[t] = m_pf;
            if (j < 31) m_pf = mg[(size_t)(j + 1) * L_SEQ];
        }
        __syncthreads();                       // staging drained

        // ---- S^T = K @ Q^T : sacc[kt], row=k, col=q(=ml) ----
        f32x4 sacc[4];
#pragma unroll
        for (int kt = 0; kt < 4; ++kt) sacc[kt] = z4;
#pragma unroll
        for (int s = 0; s < 2; ++s) {
            short8 kf[4];
#pragma unroll
            for (int kt = 0; kt < 4; ++kt)
                kf[kt] = *(const short8*)
                    &Ks[(kt * 16 + ml) * 64 + (((s * 4 + quad) ^ (ml & 7)) * 8)];
#pragma unroll
            for (int kt = 0; kt < 4; ++kt)
                sacc[kt] = __builtin_amdgcn_mfma_f32_16x16x32_bf16(
                    kf[kt], qf[s], sacc[kt], 0, 0, 0);
        }

        // ---- softmax, fixed max=0: p = mask ? exp(s/8) : exp(0)=1 ----
        const unsigned long long wq = MskL[w * 16 + ml] >> (quad * 4);
        float rs = 0.f;
        float p[4][4];
#pragma unroll
        for (int kt = 0; kt < 4; ++kt)
#pragma unroll
            for (int r = 0; r < 4; ++r) {
                const float e = fexp2(sacc[kt][r] * 0.1803368801f); // /8*log2e
                const bool bit = (wq >> (kt * 16 + r)) & 1ull;
                p[kt][r] = bit ? e : 1.0f;
                rs += p[kt][r];
            }
        rs += __shfl_xor(rs, 16);
        rs += __shfl_xor(rs, 32);
        l_i += rs;
#pragma unroll
        for (int kt = 0; kt < 4; ++kt) {
            ushort4 pk;
            pk.x = f2bf(p[kt][0]); pk.y = f2bf(p[kt][1]);
            pk.z = f2bf(p[kt][2]); pk.w = f2bf(p[kt][3]);
            const int cp = (kt * 2 + (quad >> 1)) ^ (ml & 7);
            *(ushort4*)&Ps[w][ml * 64 + cp * 8 + (quad & 1) * 4] = pk;
        }
        // own-wave P write->read: compiler lgkmcnt handles it

        // ---- O^T += V^T @ P^T ----
#pragma unroll
        for (int s = 0; s < 2; ++s) {
            const short8 pf = *(const short8*)
                &Ps[w][ml * 64 + (((s * 4 + quad) ^ (ml & 7)) * 8)];
#pragma unroll
            for (int dt = 0; dt < 4; ++dt) {
                const short8 vf = *(const short8*)
                    &Vts[(dt * 16 + ml) * 64 + (((s * 4 + quad) ^ (ml & 7)) * 8)];
                oacc[dt] = __builtin_amdgcn_mfma_f32_16x16x32_bf16(
                    vf, pf, oacc[dt], 0, 0, 0);
            }
        }
    }

    // ---- epilogue: O^T rows=d=quad*4+r(+16dt), col=q=ml ----
    const float inv = 1.0f / l_i;
    const int qrow = q0 + w * 16 + ml;
#pragma unroll
    for (int dt = 0; dt < 4; ++dt)
#pragma unroll
        for (int r = 0; r < 4; ++r) {
            const int d = dt * 16 + quad * 4 + r;
            OB[(size_t)(b * L_SEQ + qrow) * DMODEL + h * DKH + d] =
                f2bf(oacc[dt][r] * inv);
        }
}

// ---------------------------------------------------------------------------
extern "C" void kernel_launch(void* const* d_in, const int* in_sizes, int n_in,
                              void* d_out, int out_size, void* d_ws, size_t ws_size,
                              hipStream_t stream)
{
    (void)in_sizes; (void)n_in; (void)out_size; (void)ws_size;

    const float* Xq   = (const float*)d_in[0];
    const float* Xk   = (const float*)d_in[1];
    const float* Xv   = (const float*)d_in[2];
    const float* Wq   = (const float*)d_in[3];
    const float* Wk   = (const float*)d_in[4];
    const float* Wv   = (const float*)d_in[5];
    const float* Wo   = (const float*)d_in[6];
    const int*   mask = (const int*)d_in[7];
    float* out = (float*)d_out;

    char* base = (char*)d_ws;
    unsigned short*     XB  = (unsigned short*)base;                 // 24 MB
    unsigned short*     WtB = (unsigned short*)(base + (24u << 20)); //  8 MB
    unsigned short*     QKV = (unsigned short*)(base + (32u << 20)); // 24 MB
    unsigned short*     OB  = (unsigned short*)(base + (56u << 20)); //  8 MB
    unsigned long long* MWT = (unsigned long long*)(base + (64u << 20)); // 1 MB

    const size_t tsz = (size_t)MROWS * DMODEL;   // 4,194,304

    cast3<<<dim3(4096, 1, 3), 256, 0, stream>>>(Xq, Xk, Xv, XB);
    castWt<<<dim3(32, 32, 4), 256, 0, stream>>>(Wq, Wk, Wv, Wo, WtB);
    maskbits<<<dim3(32768), 256, 0, stream>>>(mask, MWT);

    gemm_bf16<<<dim3(8, 32, 3), 256, 0, stream>>>(
        XB, WtB, (void*)QKV, 0, tsz, (size_t)DMODEL * DMODEL, tsz);

    attn_mfma<<<dim3(L_SEQ / 64, NH, NB), 256, 0, stream>>>(
        QKV, QKV + tsz, QKV + 2 * tsz, MWT, OB);

    gemm_bf16<<<dim3(8, 32, 1), 256, 0, stream>>>(
        OB, WtB + 3 * (size_t)DMODEL * DMODEL, (void*)out, 1, 0, 0, 0);
}

// Round 5
// 271.472 us; speedup vs baseline: 5.1905x; 1.0973x over previous
//
#include <hip/hip_runtime.h>
#include <hip/hip_bf16.h>

#define NB 2
#define L_SEQ 2048
#define NH 16
#define DKH 64
#define DMODEL 1024
#define MROWS (NB * L_SEQ)          // 4096
#define QSCALE 0.18033688f          // 0.125 * log2(e), folded into Q

typedef __attribute__((ext_vector_type(8))) short short8;
typedef __attribute__((ext_vector_type(4))) float f32x4;

static __device__ __forceinline__ unsigned short f2bf(float f) {
    unsigned u = __float_as_uint(f);
    u += 0x7fffu + ((u >> 16) & 1u);   // RTN-even
    return (unsigned short)(u >> 16);
}

static __device__ __forceinline__ float fexp2(float x) {
#if __has_builtin(__builtin_amdgcn_exp2f)
    return __builtin_amdgcn_exp2f(x);
#else
    return __expf(x * 0.6931471806f);
#endif
}

static __device__ __forceinline__ unsigned pk_bf16(float a, float b) {
    __hip_bfloat162 h = __float22bfloat162_rn(make_float2(a, b));
    return *reinterpret_cast<unsigned*>(&h);
}

static __device__ __forceinline__ void gll16(const void* g, void* l) {
    __builtin_amdgcn_global_load_lds(
        (const __attribute__((address_space(1))) void*)g,
        (__attribute__((address_space(3))) void*)l, 16, 0, 0);
}

// ---------------------------------------------------------------------------
// cast fp32 -> bf16, 3 sources selected by blockIdx.z
// ---------------------------------------------------------------------------
__global__ __launch_bounds__(256)
void cast3(const float* __restrict__ s0, const float* __restrict__ s1,
           const float* __restrict__ s2, unsigned short* __restrict__ dst)
{
    const int z = blockIdx.z;
    const float* src = (z == 0) ? s0 : (z == 1) ? s1 : s2;
    const size_t i4 = (size_t)blockIdx.x * 256 + threadIdx.x;
    float4 v = ((const float4*)src)[i4];
    ushort4 o;
    o.x = f2bf(v.x); o.y = f2bf(v.y); o.z = f2bf(v.z); o.w = f2bf(v.w);
    ((ushort4*)(dst + (size_t)z * 4194304))[i4] = o;
}

// ---------------------------------------------------------------------------
// cast + transpose W[1024][1024] fp32 -> Wt[n][k] bf16. z selects Wq/Wk/Wv/Wo.
// ---------------------------------------------------------------------------
__global__ __launch_bounds__(256)
void castWt(const float* __restrict__ w0, const float* __restrict__ w1,
            const float* __restrict__ w2, const float* __restrict__ w3,
            unsigned short* __restrict__ dst)
{
    __shared__ float ts[32][33];
    const int z = blockIdx.z;
    const float* W = (z == 0) ? w0 : (z == 1) ? w1 : (z == 2) ? w2 : w3;
    unsigned short* Wt = dst + (size_t)z * 1048576;

    const int k0 = blockIdx.y * 32;
    const int n0 = blockIdx.x * 32;
    const int t  = threadIdx.x;
    const int r  = t >> 3;
    const int c  = (t & 7) * 4;

    float4 v = *(const float4*)&W[(size_t)(k0 + r) * DMODEL + n0 + c];
    ts[r][c + 0] = v.x; ts[r][c + 1] = v.y; ts[r][c + 2] = v.z; ts[r][c + 3] = v.w;
    __syncthreads();

    ushort4 o;
    o.x = f2bf(ts[c + 0][r]); o.y = f2bf(ts[c + 1][r]);
    o.z = f2bf(ts[c + 2][r]); o.w = f2bf(ts[c + 3][r]);
    *(ushort4*)&Wt[(size_t)(n0 + r) * DMODEL + k0 + c] = o;
}

// ---------------------------------------------------------------------------
// mask int32 [N][L][L] -> bit-packed words, [b][word][row]
// ---------------------------------------------------------------------------
__global__ __launch_bounds__(256)
void maskbits(const int* __restrict__ mask, unsigned long long* __restrict__ MWT)
{
    const int lane = threadIdx.x & 63;
    const size_t wid = (size_t)blockIdx.x * 4 + (threadIdx.x >> 6);
    const int mv = mask[wid * 64 + lane];
    const unsigned long long bits = __ballot(mv != 0);
    if (lane == 0) {
        const int b   = (int)(wid >> 16);
        const int rem = (int)(wid & 65535);
        const int row = rem >> 5;
        const int wd  = rem & 31;
        MWT[((size_t)b * 32 + wd) * L_SEQ + row] = bits;
    }
}

// ---------------------------------------------------------------------------
// bf16 MFMA GEMM, BK=64 (16 K-iters, half the barrier drains of BK=32).
// 128x128 tile, 4 waves (2x2 of 64x64), 16x16x32 mfma, XOR-swizzled LDS
// (chunk' = chunk ^ (row&7), applied on gll16 SOURCE side -> free).
// Ts (V^T transpose buffer) is unioned with As/Bs: LDS stays 32 KB.
// out_mode 0: bf16; z=0 -> Q*QSCALE [b][h][l][dk]; z=1 -> K [b][h][l][dk];
//             z=2 -> V^T [b][h][dk][l] via LDS transpose, 16B stores.
// out_mode 1: fp32 row-major (final output)
// ---------------------------------------------------------------------------
__global__ __launch_bounds__(256)
void gemm_bf16(const unsigned short* __restrict__ Aall,
               const unsigned short* __restrict__ Ball,
               void* __restrict__ Oall,
               const int out_mode, const size_t a_zs, const size_t b_zs,
               const size_t o_zs)
{
    __shared__ __align__(16) unsigned short SMEM[16384];   // 32 KB
    unsigned short* As = SMEM;            // [128][64] swizzled
    unsigned short* Bs = SMEM + 8192;     // [128][64] swizzled

    const int t    = threadIdx.x;
    const int w    = t >> 6;
    const int lane = t & 63;
    const int z    = blockIdx.z;
    const int m0   = blockIdx.y * 128;
    const int n0   = blockIdx.x * 128;

    const unsigned short* A = Aall + (size_t)z * a_zs;
    const unsigned short* B = Ball + (size_t)z * b_zs;

    const int srow = lane >> 3;                 // 0..7
    const int sc   = (lane & 7) ^ srow;         // swizzled source chunk

    const unsigned short* ag[4];
    const unsigned short* bg[4];
    unsigned short* la[4];
    unsigned short* lb[4];
#pragma unroll
    for (int j = 0; j < 4; ++j) {
        const int R = w * 32 + j * 8;
        ag[j] = A + (size_t)(m0 + R + srow) * DMODEL + sc * 8;
        bg[j] = B + (size_t)(n0 + R + srow) * DMODEL + sc * 8;
        la[j] = As + R * 64;
        lb[j] = Bs + R * 64;
    }

    const int ml = lane & 15;
    const int q  = lane >> 4;
    const int wm = (w >> 1) * 64;
    const int wn = (w & 1) * 64;

    const f32x4 z4 = {0.f, 0.f, 0.f, 0.f};
    f32x4 acc[4][4];
#pragma unroll
    for (int i = 0; i < 4; ++i)
#pragma unroll
        for (int j = 0; j < 4; ++j) acc[i][j] = z4;

    for (int kt = 0; kt < DMODEL; kt += 64) {
        __syncthreads();
#pragma unroll
        for (int j = 0; j < 4; ++j) {
            gll16(ag[j] + kt, la[j]);
            gll16(bg[j] + kt, lb[j]);
        }
        __syncthreads();

#pragma unroll
        for (int s = 0; s < 2; ++s) {
            short8 av[4], bv[4];
#pragma unroll
            for (int mt = 0; mt < 4; ++mt)
                av[mt] = *(const short8*)
                    &As[(wm + mt * 16 + ml) * 64 + (((s * 4 + q) ^ (ml & 7)) * 8)];
#pragma unroll
            for (int nt = 0; nt < 4; ++nt)
                bv[nt] = *(const short8*)
                    &Bs[(wn + nt * 16 + ml) * 64 + (((s * 4 + q) ^ (ml & 7)) * 8)];
#pragma unroll
            for (int mt = 0; mt < 4; ++mt)
#pragma unroll
                for (int nt = 0; nt < 4; ++nt)
                    acc[mt][nt] = __builtin_amdgcn_mfma_f32_16x16x32_bf16(
                        av[mt], bv[nt], acc[mt][nt], 0, 0, 0);
        }
    }

    // C/D layout: col = lane&15, row = quad*4 + reg
    if (out_mode == 0) {
        unsigned short* O = (unsigned short*)Oall + (size_t)z * o_zs;
        if (z == 2) {
            __syncthreads();                    // done reading As/Bs
            unsigned short* Ts = SMEM;          // [128][128], 32 KB
#pragma unroll
            for (int mt = 0; mt < 4; ++mt) {
                const int trow0 = wm + mt * 16 + q * 4;
                const int ch    = trow0 >> 3;
#pragma unroll
                for (int nt = 0; nt < 4; ++nt) {
                    const int tcol = wn + nt * 16 + ml;
                    const int pc   = (ch & 8) | ((ch & 7) ^ (tcol & 7));
                    ushort4 pv;
                    pv.x = f2bf(acc[mt][nt][0]); pv.y = f2bf(acc[mt][nt][1]);
                    pv.z = f2bf(acc[mt][nt][2]); pv.w = f2bf(acc[mt][nt][3]);
                    *(ushort4*)&Ts[tcol * 128 + pc * 8 + (trow0 & 7)] = pv;
                }
            }
            __syncthreads();
            const int bb = m0 >> 11;
            const int l0 = (m0 & (L_SEQ - 1)) + (t & 15) * 8;
            const int cr = t & 15;
#pragma unroll
            for (int it = 0; it < 8; ++it) {
                const int tcol = (t >> 4) + 16 * it;
                const int pc   = (cr & 8) | ((cr & 7) ^ (tcol & 7));
                short8 vv = *(const short8*)&Ts[tcol * 128 + pc * 8];
                const int n  = n0 + tcol;
                const int hh = n >> 6;
                const int dk = n & (DKH - 1);
                *(short8*)&O[((size_t)(bb * NH + hh) * DKH + dk) * L_SEQ + l0] = vv;
            }
        } else {
            const float qs = (z == 0) ? QSCALE : 1.0f;   // fold softmax scale into Q
#pragma unroll
            for (int mt = 0; mt < 4; ++mt) {
                const int gr0 = m0 + wm + mt * 16 + q * 4;
#pragma unroll
                for (int nt = 0; nt < 4; ++nt) {
                    const int col = n0 + wn + nt * 16 + ml;
                    const int hh  = col >> 6;
                    const int dk  = col & (DKH - 1);
#pragma unroll
                    for (int r = 0; r < 4; ++r) {
                        const int row = gr0 + r;
                        const int bb  = row >> 11;
                        const int l   = row & (L_SEQ - 1);
                        O[(((size_t)(bb * NH + hh) * L_SEQ + l) << 6) + dk] =
                            f2bf(acc[mt][nt][r] * qs);
                    }
                }
            }
        }
    } else {
        float* O = (float*)Oall;
#pragma unroll
        for (int mt = 0; mt < 4; ++mt) {
            const int gr0 = m0 + wm + mt * 16 + q * 4;
#pragma unroll
            for (int nt = 0; nt < 4; ++nt) {
                const int col = n0 + wn + nt * 16 + ml;
#pragma unroll
                for (int r = 0; r < 4; ++r)
                    O[(size_t)(gr0 + r) * DMODEL + col] = acc[mt][nt][r];
            }
        }
    }
}

// ---------------------------------------------------------------------------
// MFMA flash attention. Q pre-scaled by 0.125*log2e at projection, so
// p = exp2(s * maskbit): masked -> exp2(0) = 1 exactly (zero-fill semantics).
// XCD swizzle: all 32 q-blocks of one (b,h) land on one XCD (bid&7) so K/V
// (0.5 MB/pair, 4 pairs/XCD = 2 MB) stay resident in that XCD's 4 MB L2.
// ---------------------------------------------------------------------------
__global__ __launch_bounds__(256, 4)
void attn_mfma(const unsigned short* __restrict__ Qb,
               const unsigned short* __restrict__ Kb,
               const unsigned short* __restrict__ Vtb,
               const unsigned long long* __restrict__ MWT,
               unsigned short* __restrict__ OB)
{
    __shared__ __align__(16) unsigned short Qs[64 * 64];
    __shared__ __align__(16) unsigned short Ks[64 * 64];
    __shared__ __align__(16) unsigned short Vts[64 * 64];
    __shared__ __align__(16) unsigned short Ps[4][16 * 64];
    __shared__ __align__(16) unsigned long long MskL[64];

    const int t    = threadIdx.x;
    const int w    = t >> 6;
    const int lane = t & 63;
    const int ml   = lane & 15;
    const int quad = lane >> 4;

    // XCD-aware decode: pair p pinned to XCD p%8
    const int bid = blockIdx.x;
    const int p   = (bid >> 8) * 8 + (bid & 7);   // (b,h) pair 0..31
    const int jq  = (bid >> 3) & 31;              // q-tile 0..31
    const int h   = p & 15;
    const int b   = p >> 4;
    const int q0  = jq * 64;

    const size_t hoff = (size_t)(b * NH + h) * L_SEQ * DKH;
    const unsigned short* Qh  = Qb  + hoff;
    const unsigned short* Kh  = Kb  + hoff;
    const unsigned short* Vth = Vtb + hoff;     // [64][L_SEQ]

    const int srow = lane >> 3;                 // 0..7
    const int sc   = (lane & 7) ^ srow;         // swizzled source chunk

    // ---- stage Q (2 gll16 per wave) ----
    gll16(Qh + (size_t)(q0 + w * 16 + srow) * DKH + sc * 8, &Qs[(w * 16) * 64]);
    gll16(Qh + (size_t)(q0 + w * 16 + 8 + srow) * DKH + sc * 8, &Qs[(w * 16 + 8) * 64]);
    __syncthreads();

    short8 qf[2];
#pragma unroll
    for (int s = 0; s < 2; ++s)
        qf[s] = *(const short8*)
            &Qs[(w * 16 + ml) * 64 + (((s * 4 + quad) ^ (ml & 7)) * 8)];

    const unsigned short* kg0 = Kh + (size_t)(w * 16 + srow) * DKH + sc * 8;
    const unsigned short* kg1 = Kh + (size_t)(w * 16 + 8 + srow) * DKH + sc * 8;
    const unsigned short* vg0 = Vth + (size_t)(w * 16 + srow) * L_SEQ + sc * 8;
    const unsigned short* vg1 = Vth + (size_t)(w * 16 + 8 + srow) * L_SEQ + sc * 8;
    unsigned short* lk0 = &Ks[(w * 16) * 64];
    unsigned short* lk1 = &Ks[(w * 16 + 8) * 64];
    unsigned short* lv0 = &Vts[(w * 16) * 64];
    unsigned short* lv1 = &Vts[(w * 16 + 8) * 64];

    const unsigned long long* mg = MWT + (size_t)b * 32 * L_SEQ + q0 + t;
    unsigned long long m_pf = 0;
    if (t < 64) m_pf = mg[0];

    f32x4 oacc[4];
    const f32x4 z4 = {0.f, 0.f, 0.f, 0.f};
#pragma unroll
    for (int dt = 0; dt < 4; ++dt) oacc[dt] = z4;
    float l_i = 0.f;

    for (int j = 0; j < 32; ++j) {
        __syncthreads();
        gll16(kg0, lk0);  gll16(kg1, lk1);
        gll16(vg0, lv0);  gll16(vg1, lv1);
        kg0 += 64 * DKH;  kg1 += 64 * DKH;
        vg0 += 64;        vg1 += 64;
        if (t < 64) {
            MskL[t] = m_pf;
            if (j < 31) m_pf = mg[(size_t)(j + 1) * L_SEQ];
        }
        __syncthreads();

        // ---- S^T = K @ Q^T (scale already in Q) ----
        f32x4 sacc[4];
#pragma unroll
        for (int kt = 0; kt < 4; ++kt) sacc[kt] = z4;
#pragma unroll
        for (int s = 0; s < 2; ++s) {
            short8 kf[4];
#pragma unroll
            for (int kt = 0; kt < 4; ++kt)
                kf[kt] = *(const short8*)
                    &Ks[(kt * 16 + ml) * 64 + (((s * 4 + quad) ^ (ml & 7)) * 8)];
#pragma unroll
            for (int kt = 0; kt < 4; ++kt)
                sacc[kt] = __builtin_amdgcn_mfma_f32_16x16x32_bf16(
                    kf[kt], qf[s], sacc[kt], 0, 0, 0);
        }

        // ---- softmax: p = exp2(s * bit); masked -> 1 exactly ----
        const unsigned long long wq = MskL[w * 16 + ml] >> (quad * 4);
        const unsigned mlo = (unsigned)wq;
        const unsigned mhi = (unsigned)(wq >> 32);
        float rs = 0.f;
        float pr[4][4];
#pragma unroll
        for (int kt = 0; kt < 4; ++kt) {
            const unsigned word = (kt < 2) ? mlo : mhi;
            const int base = (kt & 1) * 16;
#pragma unroll
            for (int r = 0; r < 4; ++r) {
                const float mf = (float)((word >> (base + r)) & 1u);
                const float e  = fexp2(sacc[kt][r] * mf);
                pr[kt][r] = e;
                rs += e;
            }
        }
        rs += __shfl_xor(rs, 16);
        rs += __shfl_xor(rs, 32);
        l_i += rs;
#pragma unroll
        for (int kt = 0; kt < 4; ++kt) {
            uint2 pk;
            pk.x = pk_bf16(pr[kt][0], pr[kt][1]);
            pk.y = pk_bf16(pr[kt][2], pr[kt][3]);
            const int cp = (kt * 2 + (quad >> 1)) ^ (ml & 7);
            *(uint2*)&Ps[w][ml * 64 + cp * 8 + (quad & 1) * 4] = pk;
        }

        // ---- O^T += V^T @ P^T ----
#pragma unroll
        for (int s = 0; s < 2; ++s) {
            const short8 pf = *(const short8*)
                &Ps[w][ml * 64 + (((s * 4 + quad) ^ (ml & 7)) * 8)];
#pragma unroll
            for (int dt = 0; dt < 4; ++dt) {
                const short8 vf = *(const short8*)
                    &Vts[(dt * 16 + ml) * 64 + (((s * 4 + quad) ^ (ml & 7)) * 8)];
                oacc[dt] = __builtin_amdgcn_mfma_f32_16x16x32_bf16(
                    vf, pf, oacc[dt], 0, 0, 0);
            }
        }
    }

    // ---- epilogue: packed ushort4 stores, d = dt*16 + quad*4 .. +3 ----
    const float inv = 1.0f / l_i;
    const int qrow = q0 + w * 16 + ml;
#pragma unroll
    for (int dt = 0; dt < 4; ++dt) {
        ushort4 o4;
        o4.x = f2bf(oacc[dt][0] * inv);
        o4.y = f2bf(oacc[dt][1] * inv);
        o4.z = f2bf(oacc[dt][2] * inv);
        o4.w = f2bf(oacc[dt][3] * inv);
        *(ushort4*)&OB[(size_t)(b * L_SEQ + qrow) * DMODEL + h * DKH +
                       dt * 16 + quad * 4] = o4;
    }
}

// ---------------------------------------------------------------------------
extern "C" void kernel_launch(void* const* d_in, const int* in_sizes, int n_in,
                              void* d_out, int out_size, void* d_ws, size_t ws_size,
                              hipStream_t stream)
{
    (void)in_sizes; (void)n_in; (void)out_size; (void)ws_size;

    const float* Xq   = (const float*)d_in[0];
    const float* Xk   = (const float*)d_in[1];
    const float* Xv   = (const float*)d_in[2];
    const float* Wq   = (const float*)d_in[3];
    const float* Wk   = (const float*)d_in[4];
    const float* Wv   = (const float*)d_in[5];
    const float* Wo   = (const float*)d_in[6];
    const int*   mask = (const int*)d_in[7];
    float* out = (float*)d_out;

    char* base = (char*)d_ws;
    unsigned short*     XB  = (unsigned short*)base;                 // 24 MB
    unsigned short*     WtB = (unsigned short*)(base + (24u << 20)); //  8 MB
    unsigned short*     QKV = (unsigned short*)(base + (32u << 20)); // 24 MB
    unsigned short*     OB  = (unsigned short*)(base + (56u << 20)); //  8 MB
    unsigned long long* MWT = (unsigned long long*)(base + (64u << 20)); // 1 MB

    const size_t tsz = (size_t)MROWS * DMODEL;   // 4,194,304

    cast3<<<dim3(4096, 1, 3), 256, 0, stream>>>(Xq, Xk, Xv, XB);
    castWt<<<dim3(32, 32, 4), 256, 0, stream>>>(Wq, Wk, Wv, Wo, WtB);
    maskbits<<<dim3(32768), 256, 0, stream>>>(mask, MWT);

    gemm_bf16<<<dim3(8, 32, 3), 256, 0, stream>>>(
        XB, WtB, (void*)QKV, 0, tsz, (size_t)DMODEL * DMODEL, tsz);

    attn_mfma<<<dim3(1024), 256, 0, stream>>>(
        QKV, QKV + tsz, QKV + 2 * tsz, MWT, OB);

    gemm_bf16<<<dim3(8, 32, 1), 256, 0, stream>>>(
        OB, WtB + 3 * (size_t)DMODEL * DMODEL, (void*)out, 1, 0, 0, 0);
}